// Round 1
// baseline (2320.552 us; speedup 1.0000x reference)
//
#include <hip/hip_runtime.h>
#include <cstdint>
#include <cstddef>

#define N_  32
#define C_  64
#define T_  256
#define V_  25
#define R_  8
#define O_  64
#define K_  5
#define NU_ 17

#define OB 4    // o per block in k_main
#define TB 64   // t per block in k_main

#define OUT_ELEMS    ((size_t)N_ * O_ * T_ * V_)        // 13,107,200
#define GRAPHS_ELEMS ((size_t)K_ * N_ * O_ * V_ * V_)   // 6,400,000

// ---------------------------------------------------------------------------
// Kernel 1: temporal mean pool  pool[n,c,v] = mean_t x[n,c,t,v]
// grid = N_*C_ blocks, 256 threads (= T_), thread t reads 25 consecutive floats
// ---------------------------------------------------------------------------
__global__ void k_pool(const float* __restrict__ x, float* __restrict__ pool) {
    int nc = blockIdx.x;          // n*C + c
    int t  = threadIdx.x;         // 0..255 == T_
    const float* px = x + ((size_t)nc * T_ + t) * V_;
    float acc[V_];
#pragma unroll
    for (int v = 0; v < V_; ++v) acc[v] = px[v];
    // wave64 butterfly reduce
#pragma unroll
    for (int off = 32; off > 0; off >>= 1) {
#pragma unroll
        for (int v = 0; v < V_; ++v) acc[v] += __shfl_down(acc[v], off, 64);
    }
    __shared__ float sm[4][V_];
    int wave = t >> 6, lane = t & 63;
    if (lane == 0) {
#pragma unroll
        for (int v = 0; v < V_; ++v) sm[wave][v] = acc[v];
    }
    __syncthreads();
    if (t < V_) {
        float s = sm[0][t] + sm[1][t] + sm[2][t] + sm[3][t];
        pool[(size_t)nc * V_ + t] = s * (1.0f / T_);
    }
}

// ---------------------------------------------------------------------------
// Kernel 2: t2[k,n,r,v] = b2 + W2·pool ;  tS = (v<17 ? b11+W11·pool : b12+W12·pool)
// grid = K_*N_ blocks, 256 threads: r = tid>>5 (8), v = tid&31 (<25 active)
// ---------------------------------------------------------------------------
__global__ void k_tvals(const float* __restrict__ pool,
                        const float* __restrict__ W11, const float* __restrict__ b11,
                        const float* __restrict__ W12, const float* __restrict__ b12,
                        const float* __restrict__ W2,  const float* __restrict__ b2,
                        float* __restrict__ t2o, float* __restrict__ tSo) {
    int kn = blockIdx.x;
    int k = kn / N_, n = kn % N_;
    int tid = threadIdx.x;
    int r = tid >> 5, v = tid & 31;
    if (v >= V_) return;
    const float* pp = pool + (size_t)n * C_ * V_ + v;          // stride V_ per c
    const float* w2 = W2 + ((size_t)k * R_ + r) * C_;
    const float* w1 = ((v < NU_) ? W11 : W12) + ((size_t)k * R_ + r) * C_;
    float a2 = b2[k * R_ + r];
    float a1 = (v < NU_) ? b11[k * R_ + r] : b12[k * R_ + r];
    for (int c = 0; c < C_; ++c) {
        float p = pp[(size_t)c * V_];
        a2 += w2[c] * p;
        a1 += w1[c] * p;
    }
    size_t idx = (((size_t)k * N_ + n) * R_ + r) * V_ + v;
    t2o[idx] = a2;
    tSo[idx] = a1;
}

// ---------------------------------------------------------------------------
// Kernel 3: F[r,u,v] = tanh(tS[k_u,n,r,u] - t2[k_u,n,r,v]),
//           k_u = (k+1)%K for u<17 (rotation), else k.
// graphs[k,n,o,u,v] = b4[k,o] + sum_r W4[k,o,r]*F[r,u,v]   (written to d_out)
// grid = K_*N_ blocks, 256 threads.
// ---------------------------------------------------------------------------
__global__ void k_graphs(const float* __restrict__ t2v, const float* __restrict__ tSv,
                         const float* __restrict__ W4, const float* __restrict__ b4,
                         float* __restrict__ graphs) {
    int kn = blockIdx.x;
    int k = kn / N_, n = kn % N_;
    int kup = (k + 1) % K_;
    __shared__ float F[R_][V_ * V_];       // 8 x 625 = 20 KB
    __shared__ float w4s[O_][R_];
    __shared__ float b4s[O_];
    int tid = threadIdx.x;
    for (int i = tid; i < O_ * R_; i += 256) w4s[i / R_][i % R_] = W4[(size_t)k * O_ * R_ + i];
    if (tid < O_) b4s[tid] = b4[k * O_ + tid];
    for (int idx = tid; idx < R_ * V_ * V_; idx += 256) {
        int r = idx / (V_ * V_), uv = idx % (V_ * V_);
        int u = uv / V_, v = uv % V_;
        int ks = (u < NU_) ? kup : k;
        size_t base = (((size_t)ks * N_ + n) * R_ + r) * V_;
        F[r][uv] = tanhf(tSv[base + u] - t2v[base + v]);
    }
    __syncthreads();
    float* gout = graphs + ((size_t)k * N_ + n) * O_ * (V_ * V_);
    for (int idx = tid; idx < O_ * V_ * V_; idx += 256) {
        int o = idx / (V_ * V_), uv = idx % (V_ * V_);
        float a = b4s[o];
#pragma unroll
        for (int r = 0; r < R_; ++r) a += w4s[o][r] * F[r][uv];
        gout[idx] = a;
    }
}

// ---------------------------------------------------------------------------
// Kernel 4 (dominant): out[n,o,t,u] = sum_k sum_v (graphs+A)[k,n,o,u,v] * x2[k][v]
//   where x2[k][v] = b3[k,o] + sum_c W3[k,o,c] * x[n,c,t,v]
// block = (n, 4 o's, 64 t's); thread = (o_local = wave, t = lane).
// x2[5][25] lives in registers (static indexing only).
// ---------------------------------------------------------------------------
__global__ __launch_bounds__(256, 2) void k_main(
    const float* __restrict__ x, const float* __restrict__ graphs,
    const float* __restrict__ A, const float* __restrict__ W3,
    const float* __restrict__ b3, float* __restrict__ out) {
    int bid = blockIdx.x;
    int tb = bid & 3;              // T_/TB = 4
    int ob = (bid >> 2) & 15;      // O_/OB = 16
    int n  = bid >> 6;
    int tid = threadIdx.x;
    int ol = tid >> 6;             // wave index = o_local
    int tl = tid & 63;
    int t = tb * TB + tl;
    int o = ob * OB + ol;

    // Gs rows padded to 28 floats -> 112B row stride (16B aligned, b128-able)
    __shared__ float Gs[K_][OB][V_][28];    // 56 KB
    __shared__ float W3s[K_][OB][C_];       // 5 KB
    __shared__ float b3s[K_][OB];

    for (int i = tid; i < K_ * OB * V_ * V_; i += 256) {
        int k   = i / (OB * V_ * V_);
        int rem = i % (OB * V_ * V_);
        int oo  = rem / (V_ * V_);
        int uv  = rem % (V_ * V_);
        Gs[k][oo][uv / V_][uv % V_] =
            graphs[(((size_t)k * N_ + n) * O_ + ob * OB + oo) * (V_ * V_) + uv]
            + A[k * V_ * V_ + uv];
    }
    for (int i = tid; i < K_ * OB * C_; i += 256) {
        int k   = i / (OB * C_);
        int rem = i % (OB * C_);
        int oo  = rem / C_, c = rem % C_;
        W3s[k][oo][c] = W3[((size_t)k * O_ + ob * OB + oo) * C_ + c];
    }
    if (tid < K_ * OB) b3s[tid / OB][tid % OB] = b3[(tid / OB) * O_ + ob * OB + tid % OB];
    __syncthreads();

    float x2[K_][V_];
#pragma unroll
    for (int k = 0; k < K_; ++k)
#pragma unroll
        for (int v = 0; v < V_; ++v) x2[k][v] = b3s[k][ol];

    const float* xb = x + ((size_t)n * C_ * T_ + t) * V_;
    for (int c = 0; c < C_; ++c) {
        const float* p = xb + (size_t)c * T_ * V_;
        float xv[V_];
#pragma unroll
        for (int v = 0; v < V_; ++v) xv[v] = p[v];
#pragma unroll
        for (int k = 0; k < K_; ++k) {
            float w = W3s[k][ol][c];
#pragma unroll
            for (int v = 0; v < V_; ++v) x2[k][v] += w * xv[v];
        }
    }

    float acc[V_];
#pragma unroll
    for (int u = 0; u < V_; ++u) acc[u] = 0.0f;
#pragma unroll
    for (int k = 0; k < K_; ++k) {
        for (int u = 0; u < V_; ++u) {   // u rolled: keeps code size sane
            float g[V_];
#pragma unroll
            for (int v = 0; v < V_; ++v) g[v] = Gs[k][ol][u][v];
#pragma unroll
            for (int v = 0; v < V_; ++v) acc[u] += g[v] * x2[k][v];
        }
    }
    float* po = out + (((size_t)n * O_ + o) * T_ + t) * V_;
#pragma unroll
    for (int u = 0; u < V_; ++u) po[u] = acc[u];
}

// ---------------------------------------------------------------------------
extern "C" void kernel_launch(void* const* d_in, const int* in_sizes, int n_in,
                              void* d_out, int out_size, void* d_ws, size_t ws_size,
                              hipStream_t stream) {
    const float* x   = (const float*)d_in[0];
    const float* A   = (const float*)d_in[1];
    const float* W11 = (const float*)d_in[2];
    const float* b11 = (const float*)d_in[3];
    const float* W12 = (const float*)d_in[4];
    const float* b12 = (const float*)d_in[5];
    const float* W2  = (const float*)d_in[6];
    const float* b2  = (const float*)d_in[7];
    const float* W3  = (const float*)d_in[8];
    const float* b3  = (const float*)d_in[9];
    const float* W4  = (const float*)d_in[10];
    const float* b4  = (const float*)d_in[11];

    float* out    = (float*)d_out;
    float* graphs = out + OUT_ELEMS;   // second tuple element, flat after `out`

    const size_t poolElems = (size_t)N_ * C_ * V_;     // 51,200
    const size_t tElems    = (size_t)K_ * N_ * R_ * V_; // 32,000
    const size_t needBytes = (poolElems + 2 * tElems) * sizeof(float);
    // Prefer d_ws; fall back to the `out` region (fully rewritten by k_main later).
    float* scratch = (ws_size >= needBytes) ? (float*)d_ws : out;
    float* pool = scratch;
    float* t2v  = scratch + poolElems;
    float* tSv  = t2v + tElems;

    k_pool  <<<N_ * C_, 256, 0, stream>>>(x, pool);
    k_tvals <<<K_ * N_, 256, 0, stream>>>(pool, W11, b11, W12, b12, W2, b2, t2v, tSv);
    k_graphs<<<K_ * N_, 256, 0, stream>>>(t2v, tSv, W4, b4, graphs);
    k_main  <<<N_ * (O_ / OB) * (T_ / TB), 256, 0, stream>>>(x, graphs, A, W3, b3, out);
}

// Round 2
// 358.857 us; speedup vs baseline: 6.4665x; 6.4665x over previous
//
#include <hip/hip_runtime.h>
#include <cstdint>
#include <cstddef>

#define N_  32
#define C_  64
#define T_  256
#define V_  25
#define R_  8
#define O_  64
#define K_  5
#define NU_ 17

#define OB 4    // o per block in k_main
#define TB 64   // t per block in k_main

#define OUT_ELEMS    ((size_t)N_ * O_ * T_ * V_)        // 13,107,200
#define GRAPHS_ELEMS ((size_t)K_ * N_ * O_ * V_ * V_)   // 6,400,000

// ---------------------------------------------------------------------------
// Kernel 1: temporal mean pool  pool[n,c,v] = mean_t x[n,c,t,v]
// ---------------------------------------------------------------------------
__global__ void k_pool(const float* __restrict__ x, float* __restrict__ pool) {
    int nc = blockIdx.x;          // n*C + c
    int t  = threadIdx.x;         // 0..255 == T_
    const float* px = x + ((size_t)nc * T_ + t) * V_;
    float acc[V_];
#pragma unroll
    for (int v = 0; v < V_; ++v) acc[v] = px[v];
#pragma unroll
    for (int off = 32; off > 0; off >>= 1) {
#pragma unroll
        for (int v = 0; v < V_; ++v) acc[v] += __shfl_down(acc[v], off, 64);
    }
    __shared__ float sm[4][V_];
    int wave = t >> 6, lane = t & 63;
    if (lane == 0) {
#pragma unroll
        for (int v = 0; v < V_; ++v) sm[wave][v] = acc[v];
    }
    __syncthreads();
    if (t < V_) {
        float s = sm[0][t] + sm[1][t] + sm[2][t] + sm[3][t];
        pool[(size_t)nc * V_ + t] = s * (1.0f / T_);
    }
}

// ---------------------------------------------------------------------------
// Kernel 2: t2[k,n,r,v] = b2 + W2·pool ;  tS = (v<17 ? b11+W11·pool : b12+W12·pool)
// ---------------------------------------------------------------------------
__global__ void k_tvals(const float* __restrict__ pool,
                        const float* __restrict__ W11, const float* __restrict__ b11,
                        const float* __restrict__ W12, const float* __restrict__ b12,
                        const float* __restrict__ W2,  const float* __restrict__ b2,
                        float* __restrict__ t2o, float* __restrict__ tSo) {
    int kn = blockIdx.x;
    int k = kn / N_, n = kn % N_;
    int tid = threadIdx.x;
    int r = tid >> 5, v = tid & 31;
    if (v >= V_) return;
    const float* pp = pool + (size_t)n * C_ * V_ + v;
    const float* w2 = W2 + ((size_t)k * R_ + r) * C_;
    const float* w1 = ((v < NU_) ? W11 : W12) + ((size_t)k * R_ + r) * C_;
    float a2 = b2[k * R_ + r];
    float a1 = (v < NU_) ? b11[k * R_ + r] : b12[k * R_ + r];
    for (int c = 0; c < C_; ++c) {
        float p = pp[(size_t)c * V_];
        a2 += w2[c] * p;
        a1 += w1[c] * p;
    }
    size_t idx = (((size_t)k * N_ + n) * R_ + r) * V_ + v;
    t2o[idx] = a2;
    tSo[idx] = a1;
}

// ---------------------------------------------------------------------------
// Kernel 3: graphs[k,n,o,u,v] = b4 + sum_r W4[k,o,r]*tanh(tS[ku,n,r,u]-t2[ku,n,r,v])
// ---------------------------------------------------------------------------
__global__ void k_graphs(const float* __restrict__ t2v, const float* __restrict__ tSv,
                         const float* __restrict__ W4, const float* __restrict__ b4,
                         float* __restrict__ graphs) {
    int kn = blockIdx.x;
    int k = kn / N_, n = kn % N_;
    int kup = (k + 1) % K_;
    __shared__ float F[R_][V_ * V_];       // 8 x 625 = 20 KB
    __shared__ float w4s[O_][R_];
    __shared__ float b4s[O_];
    int tid = threadIdx.x;
    for (int i = tid; i < O_ * R_; i += 256) w4s[i / R_][i % R_] = W4[(size_t)k * O_ * R_ + i];
    if (tid < O_) b4s[tid] = b4[k * O_ + tid];
    for (int idx = tid; idx < R_ * V_ * V_; idx += 256) {
        int r = idx / (V_ * V_), uv = idx % (V_ * V_);
        int u = uv / V_, v = uv % V_;
        int ks = (u < NU_) ? kup : k;
        size_t base = (((size_t)ks * N_ + n) * R_ + r) * V_;
        F[r][uv] = tanhf(tSv[base + u] - t2v[base + v]);
    }
    __syncthreads();
    float* gout = graphs + ((size_t)k * N_ + n) * O_ * (V_ * V_);
    for (int idx = tid; idx < O_ * V_ * V_; idx += 256) {
        int o = idx / (V_ * V_), uv = idx % (V_ * V_);
        float a = b4s[o];
#pragma unroll
        for (int r = 0; r < R_; ++r) a += w4s[o][r] * F[r][uv];
        gout[idx] = a;
    }
}

// ---------------------------------------------------------------------------
// Kernel 4 (dominant): out[n,o,t,u] = sum_k sum_v (graphs+A)[k,n,o,u,v] * x2[k][v]
//   x2[k][v] = b3[k,o] + sum_c W3[k,o,c] * x[n,c,t,v]
// block = (n, 4 o's, 64 t's); thread = (o_local = wave, t = lane).
// ALL per-thread arrays statically indexed (full unroll) — rule #20.
// ---------------------------------------------------------------------------
__global__ __launch_bounds__(256, 2) void k_main(
    const float* __restrict__ x, const float* __restrict__ graphs,
    const float* __restrict__ A, const float* __restrict__ W3,
    const float* __restrict__ b3, float* __restrict__ out) {
    int bid = blockIdx.x;
    int tb = bid & 3;              // T_/TB = 4
    int ob = (bid >> 2) & 15;      // O_/OB = 16
    int n  = bid >> 6;
    int tid = threadIdx.x;
    int ol = tid >> 6;             // wave index = o_local
    int tl = tid & 63;
    int t = tb * TB + tl;
    int o = ob * OB + ol;

    // Gs rows padded to 28 floats -> 112B row stride (16B aligned, b128-able).
    // Contraction reads are wave-uniform (broadcast) -> conflict-free.
    __shared__ float Gs[K_][OB][V_][28];    // 56 KB
    __shared__ float W3s[K_][OB][C_];       // 5 KB
    __shared__ float b3s[K_][OB];

    for (int i = tid; i < K_ * OB * V_ * V_; i += 256) {
        int k   = i / (OB * V_ * V_);
        int rem = i % (OB * V_ * V_);
        int oo  = rem / (V_ * V_);
        int uv  = rem % (V_ * V_);
        Gs[k][oo][uv / V_][uv % V_] =
            graphs[(((size_t)k * N_ + n) * O_ + ob * OB + oo) * (V_ * V_) + uv]
            + A[k * V_ * V_ + uv];
    }
    for (int i = tid; i < K_ * OB * C_; i += 256) {
        int k   = i / (OB * C_);
        int rem = i % (OB * C_);
        int oo  = rem / C_, c = rem % C_;
        W3s[k][oo][c] = W3[((size_t)k * O_ + ob * OB + oo) * C_ + c];
    }
    if (tid < K_ * OB) b3s[tid / OB][tid % OB] = b3[(tid / OB) * O_ + ob * OB + tid % OB];
    __syncthreads();

    // ---- phase 1: x2[k][v] in registers (125 floats, static indexing) ----
    float x2[K_][V_];
#pragma unroll
    for (int k = 0; k < K_; ++k)
#pragma unroll
        for (int v = 0; v < V_; ++v) x2[k][v] = b3s[k][ol];

    const float* xb = x + ((size_t)n * C_ * T_ + t) * V_;
    for (int c = 0; c < C_; ++c) {
        const float* p = xb + (size_t)c * T_ * V_;
        float xv[V_];
#pragma unroll
        for (int v = 0; v < V_; ++v) xv[v] = p[v];
#pragma unroll
        for (int k = 0; k < K_; ++k) {
            float w = W3s[k][ol][c];
#pragma unroll
            for (int v = 0; v < V_; ++v) x2[k][v] += w * xv[v];
        }
    }

    // ---- phase 2: contraction, FULLY UNROLLED (acc static-indexed) ----
    float acc[V_];
#pragma unroll
    for (int u = 0; u < V_; ++u) acc[u] = 0.0f;
#pragma unroll
    for (int k = 0; k < K_; ++k) {
#pragma unroll
        for (int u = 0; u < V_; ++u) {
            const float* gr = &Gs[k][ol][u][0];
            float s = 0.0f;
#pragma unroll
            for (int v = 0; v < V_; ++v) s += gr[v] * x2[k][v];
            acc[u] += s;
        }
    }

    float* po = out + (((size_t)n * O_ + o) * T_ + t) * V_;
#pragma unroll
    for (int u = 0; u < V_; ++u) po[u] = acc[u];
}

// ---------------------------------------------------------------------------
extern "C" void kernel_launch(void* const* d_in, const int* in_sizes, int n_in,
                              void* d_out, int out_size, void* d_ws, size_t ws_size,
                              hipStream_t stream) {
    const float* x   = (const float*)d_in[0];
    const float* A   = (const float*)d_in[1];
    const float* W11 = (const float*)d_in[2];
    const float* b11 = (const float*)d_in[3];
    const float* W12 = (const float*)d_in[4];
    const float* b12 = (const float*)d_in[5];
    const float* W2  = (const float*)d_in[6];
    const float* b2  = (const float*)d_in[7];
    const float* W3  = (const float*)d_in[8];
    const float* b3  = (const float*)d_in[9];
    const float* W4  = (const float*)d_in[10];
    const float* b4  = (const float*)d_in[11];

    float* out    = (float*)d_out;
    float* graphs = out + OUT_ELEMS;   // second tuple element, flat after `out`

    const size_t poolElems = (size_t)N_ * C_ * V_;      // 51,200
    const size_t tElems    = (size_t)K_ * N_ * R_ * V_; // 32,000
    const size_t needBytes = (poolElems + 2 * tElems) * sizeof(float);
    float* scratch = (ws_size >= needBytes) ? (float*)d_ws : out;
    float* pool = scratch;
    float* t2v  = scratch + poolElems;
    float* tSv  = t2v + tElems;

    k_pool  <<<N_ * C_, 256, 0, stream>>>(x, pool);
    k_tvals <<<K_ * N_, 256, 0, stream>>>(pool, W11, b11, W12, b12, W2, b2, t2v, tSv);
    k_graphs<<<K_ * N_, 256, 0, stream>>>(t2v, tSv, W4, b4, graphs);
    k_main  <<<N_ * (O_ / OB) * (T_ / TB), 256, 0, stream>>>(x, graphs, A, W3, b3, out);
}